// Round 1
// baseline (273.123 us; speedup 1.0000x reference)
//
#include <hip/hip_runtime.h>
#include <hip/hip_bf16.h>

#define D 128            // EMBED_DIM
#define G 3              // NUM_GROUPS

// ---------------------------------------------------------------------------
// Kernel 1: per-node linear(128->3) + softmax -> coeff[n] as float4 (w=0)
// one wave (64 lanes) per node; each lane owns 2 feature dims (float2)
// ---------------------------------------------------------------------------
__global__ void lg_coeff_kernel(const float* __restrict__ X,
                                const float* __restrict__ W,
                                const float* __restrict__ b,
                                float4* __restrict__ coeff, int n) {
    int node = (int)((blockIdx.x * (size_t)blockDim.x + threadIdx.x) >> 6);
    int lane = threadIdx.x & 63;
    if (node >= n) return;
    float2 x = ((const float2*)(X + (size_t)node * D))[lane];
    int d0 = lane * 2;
    float s0 = x.x * W[d0 * G + 0] + x.y * W[(d0 + 1) * G + 0];
    float s1 = x.x * W[d0 * G + 1] + x.y * W[(d0 + 1) * G + 1];
    float s2 = x.x * W[d0 * G + 2] + x.y * W[(d0 + 1) * G + 2];
    #pragma unroll
    for (int off = 32; off; off >>= 1) {
        s0 += __shfl_xor(s0, off);
        s1 += __shfl_xor(s1, off);
        s2 += __shfl_xor(s2, off);
    }
    s0 += b[0]; s1 += b[1]; s2 += b[2];     // T = 1.0
    float m = fmaxf(s0, fmaxf(s1, s2));
    float e0 = __expf(s0 - m), e1 = __expf(s1 - m), e2 = __expf(s2 - m);
    float inv = 1.0f / (e0 + e1 + e2);
    if (lane == 0) coeff[node] = make_float4(e0 * inv, e1 * inv, e2 * inv, 0.0f);
}

// ---------------------------------------------------------------------------
// Kernel 2: degree histogram (int atomics)
// ---------------------------------------------------------------------------
__global__ void lg_deg_kernel(const int* __restrict__ dst, int* __restrict__ deg, int E) {
    int e = (int)(blockIdx.x * (size_t)blockDim.x + threadIdx.x);
    if (e < E) atomicAdd(&deg[dst[e]], 1);
}

// ---------------------------------------------------------------------------
// Kernel 3: single-block exclusive scan: off[0..n] from deg[0..n-1]
// 1024 threads, each owns a contiguous chunk; Hillis-Steele over chunk sums
// ---------------------------------------------------------------------------
__global__ void lg_scan_kernel(const int* __restrict__ deg, int* __restrict__ off, int n) {
    __shared__ int sums[1024];
    int tid = threadIdx.x;
    int chunk = (n + 1023) / 1024;
    int start = tid * chunk;
    int end   = min(start + chunk, n);
    int s = 0;
    for (int i = start; i < end; i++) s += deg[i];
    sums[tid] = s;
    __syncthreads();
    for (int d = 1; d < 1024; d <<= 1) {
        int v = (tid >= d) ? sums[tid - d] : 0;
        __syncthreads();
        sums[tid] += v;
        __syncthreads();
    }
    int run = (tid == 0) ? 0 : sums[tid - 1];   // exclusive prefix of this chunk
    for (int i = start; i < end; i++) { off[i] = run; run += deg[i]; }
    if (tid == 1023) off[n] = run;              // last thread's chunk is empty or last -> total
}

// ---------------------------------------------------------------------------
// Kernel 4: counting-sort edges by dst into CSR (store src index)
// ---------------------------------------------------------------------------
__global__ void lg_fill_kernel(const int* __restrict__ src, const int* __restrict__ dst,
                               const int* __restrict__ off, int* __restrict__ cnt,
                               int* __restrict__ csr, int E) {
    int e = (int)(blockIdx.x * (size_t)blockDim.x + threadIdx.x);
    if (e >= E) return;
    int d = dst[e];
    int pos = off[d] + atomicAdd(&cnt[d], 1);
    csr[pos] = src[e];
}

// ---------------------------------------------------------------------------
// Kernel 5: per-node aggregation. One wave per dst node, lanes own 2 dims.
// out[n,:] = (1/max(deg,1)) * sum_e dot3(coeff[n],coeff[src_e]) * X[src_e,:]
// ---------------------------------------------------------------------------
__global__ void lg_agg_kernel(const float* __restrict__ X,
                              const float4* __restrict__ coeff,
                              const int* __restrict__ off,
                              const int* __restrict__ csr,
                              float* __restrict__ out, int n) {
    int node = (int)((blockIdx.x * (size_t)blockDim.x + threadIdx.x) >> 6);
    int lane = threadIdx.x & 63;
    if (node >= n) return;
    float4 cn = coeff[node];
    int beg = off[node], end = off[node + 1];
    float accx = 0.0f, accy = 0.0f;
    for (int i = beg; i < end; i++) {
        int s = csr[i];                          // wave-uniform
        float4 cs = coeff[s];
        float se = cn.x * cs.x + cn.y * cs.y + cn.z * cs.z;
        float2 x = ((const float2*)(X + (size_t)s * D))[lane];
        accx = fmaf(se, x.x, accx);
        accy = fmaf(se, x.y, accy);
    }
    float invd = 1.0f / fmaxf((float)(end - beg), 1.0f);
    float2 r = make_float2(accx * invd, accy * invd);
    ((float2*)(out + (size_t)node * D))[lane] = r;
}

// ---------------------------------------------------------------------------
// Fallback path (if ws too small for CSR): float-atomic scatter
// ---------------------------------------------------------------------------
__global__ void lg_scatter_kernel(const float* __restrict__ X,
                                  const float4* __restrict__ coeff,
                                  const int* __restrict__ src, const int* __restrict__ dst,
                                  float* __restrict__ out, int E) {
    int e = (int)((blockIdx.x * (size_t)blockDim.x + threadIdx.x) >> 6);
    int lane = threadIdx.x & 63;
    if (e >= E) return;
    int s = src[e], d = dst[e];
    float4 cs = coeff[s], cd = coeff[d];
    float se = cs.x * cd.x + cs.y * cd.y + cs.z * cd.z;
    float2 x = ((const float2*)(X + (size_t)s * D))[lane];
    atomicAdd(&out[(size_t)d * D + lane * 2 + 0], se * x.x);
    atomicAdd(&out[(size_t)d * D + lane * 2 + 1], se * x.y);
}

__global__ void lg_scale_kernel(float* __restrict__ out, const int* __restrict__ deg, int n) {
    int node = (int)((blockIdx.x * (size_t)blockDim.x + threadIdx.x) >> 6);
    int lane = threadIdx.x & 63;
    if (node >= n) return;
    float invd = 1.0f / fmaxf((float)deg[node], 1.0f);
    float2* p = (float2*)(out + (size_t)node * D);
    float2 v = p[lane];
    p[lane] = make_float2(v.x * invd, v.y * invd);
}

extern "C" void kernel_launch(void* const* d_in, const int* in_sizes, int n_in,
                              void* d_out, int out_size, void* d_ws, size_t ws_size,
                              hipStream_t stream) {
    const float* X   = (const float*)d_in[0];
    const int*   src = (const int*)d_in[1];
    const int*   dst = (const int*)d_in[2];
    const float* W   = (const float*)d_in[3];
    const float* b   = (const float*)d_in[4];
    float* out = (float*)d_out;
    int n = in_sizes[0] / D;
    int E = in_sizes[1];

    char* ws = (char*)d_ws;
    size_t p = 0;
    auto alloc = [&](size_t bytes) -> void* {
        void* r = ws + p;
        p = (p + bytes + 255) & ~(size_t)255;
        return r;
    };
    float4* coeff = (float4*)alloc((size_t)n * sizeof(float4));
    int*    deg   = (int*)alloc((size_t)n * sizeof(int));
    int*    cnt   = (int*)alloc((size_t)n * sizeof(int));
    int*    off   = (int*)alloc((size_t)(n + 1) * sizeof(int));
    int*    csr   = (int*)alloc((size_t)E * sizeof(int));
    bool full_path = (p <= ws_size);

    int node_blocks = (n + 3) / 4;      // 4 waves (nodes) per 256-thread block
    int edge_blocks = (E + 255) / 256;

    if (full_path) {
        hipMemsetAsync(deg, 0, (size_t)n * sizeof(int), stream);
        hipMemsetAsync(cnt, 0, (size_t)n * sizeof(int), stream);
        lg_coeff_kernel<<<node_blocks, 256, 0, stream>>>(X, W, b, coeff, n);
        lg_deg_kernel<<<edge_blocks, 256, 0, stream>>>(dst, deg, E);
        lg_scan_kernel<<<1, 1024, 0, stream>>>(deg, off, n);
        lg_fill_kernel<<<edge_blocks, 256, 0, stream>>>(src, dst, off, cnt, csr, E);
        lg_agg_kernel<<<node_blocks, 256, 0, stream>>>(X, coeff, off, csr, out, n);
    } else {
        // minimal-workspace fallback: coeff + deg only (~1 MB)
        hipMemsetAsync(deg, 0, (size_t)n * sizeof(int), stream);
        hipMemsetAsync(out, 0, (size_t)n * D * sizeof(float), stream);
        lg_coeff_kernel<<<node_blocks, 256, 0, stream>>>(X, W, b, coeff, n);
        lg_deg_kernel<<<edge_blocks, 256, 0, stream>>>(dst, deg, E);
        lg_scatter_kernel<<<(E + 3) / 4, 256, 0, stream>>>(X, coeff, src, dst, out, E);
        lg_scale_kernel<<<node_blocks, 256, 0, stream>>>(out, deg, n);
    }
}

// Round 2
// 211.432 us; speedup vs baseline: 1.2918x; 1.2918x over previous
//
#include <hip/hip_runtime.h>
#include <hip/hip_bf16.h>

#define D 128            // EMBED_DIM
#define G 3              // NUM_GROUPS

// ---------------------------------------------------------------------------
// Kernel 1: per-node linear(128->3) + softmax -> coeff[n] (float4, w=0)
// Also emits a bf16 copy of X for the gather phase (halves gather traffic).
// one wave (64 lanes) per node; each lane owns 2 feature dims (float2)
// ---------------------------------------------------------------------------
__global__ void lg_coeff_kernel(const float* __restrict__ X,
                                const float* __restrict__ W,
                                const float* __restrict__ b,
                                float4* __restrict__ coeff,
                                __hip_bfloat16* __restrict__ Xh,   // may be null
                                int n) {
    int node = (int)((blockIdx.x * (size_t)blockDim.x + threadIdx.x) >> 6);
    int lane = threadIdx.x & 63;
    if (node >= n) return;
    float2 x = ((const float2*)(X + (size_t)node * D))[lane];
    if (Xh) {
        __hip_bfloat162 h;
        h.x = __float2bfloat16(x.x);
        h.y = __float2bfloat16(x.y);
        ((__hip_bfloat162*)(Xh + (size_t)node * D))[lane] = h;
    }
    int d0 = lane * 2;
    float s0 = x.x * W[d0 * G + 0] + x.y * W[(d0 + 1) * G + 0];
    float s1 = x.x * W[d0 * G + 1] + x.y * W[(d0 + 1) * G + 1];
    float s2 = x.x * W[d0 * G + 2] + x.y * W[(d0 + 1) * G + 2];
    #pragma unroll
    for (int off = 32; off; off >>= 1) {
        s0 += __shfl_xor(s0, off);
        s1 += __shfl_xor(s1, off);
        s2 += __shfl_xor(s2, off);
    }
    s0 += b[0]; s1 += b[1]; s2 += b[2];     // T = 1.0
    float m = fmaxf(s0, fmaxf(s1, s2));
    float e0 = __expf(s0 - m), e1 = __expf(s1 - m), e2 = __expf(s2 - m);
    float inv = 1.0f / (e0 + e1 + e2);
    if (lane == 0) coeff[node] = make_float4(e0 * inv, e1 * inv, e2 * inv, 0.0f);
}

// ---------------------------------------------------------------------------
// Kernel 2: degree histogram (int atomics)
// ---------------------------------------------------------------------------
__global__ void lg_deg_kernel(const int* __restrict__ dst, int* __restrict__ deg, int E) {
    int e = (int)(blockIdx.x * (size_t)blockDim.x + threadIdx.x);
    if (e < E) atomicAdd(&deg[dst[e]], 1);
}

// ---------------------------------------------------------------------------
// Kernel 3: single-block exclusive scan: off[0..n] from deg[0..n-1]
// ---------------------------------------------------------------------------
__global__ void lg_scan_kernel(const int* __restrict__ deg, int* __restrict__ off, int n) {
    __shared__ int sums[1024];
    int tid = threadIdx.x;
    int chunk = (n + 1023) / 1024;
    int start = tid * chunk;
    int end   = min(start + chunk, n);
    int s = 0;
    for (int i = start; i < end; i++) s += deg[i];
    sums[tid] = s;
    __syncthreads();
    for (int d = 1; d < 1024; d <<= 1) {
        int v = (tid >= d) ? sums[tid - d] : 0;
        __syncthreads();
        sums[tid] += v;
        __syncthreads();
    }
    int run = (tid == 0) ? 0 : sums[tid - 1];
    for (int i = start; i < end; i++) { off[i] = run; run += deg[i]; }
    if (tid == 1023) off[n] = run;
}

// ---------------------------------------------------------------------------
// Kernel 4: counting-sort edges by dst into CSR, with per-edge scalar weight
// w_e = dot3(coeff[dst], coeff[src]) baked in. Payload int2 = (src, w-bits).
// ---------------------------------------------------------------------------
__global__ void lg_fill_kernel(const int* __restrict__ src, const int* __restrict__ dst,
                               const float4* __restrict__ coeff,
                               const int* __restrict__ off, int* __restrict__ cnt,
                               int2* __restrict__ csrw, int E) {
    int e = (int)(blockIdx.x * (size_t)blockDim.x + threadIdx.x);
    if (e >= E) return;
    int s = src[e], d = dst[e];
    float4 cs = coeff[s], cd = coeff[d];
    float w = cs.x * cd.x + cs.y * cd.y + cs.z * cd.z;
    int pos = off[d] + atomicAdd(&cnt[d], 1);
    csrw[pos] = make_int2(s, __float_as_int(w));
}

// ---------------------------------------------------------------------------
// Kernel 5: per-node aggregation, bf16 gathers.
// One wave per dst node; lanes own 2 dims. Wave coalesce-loads up to 64
// (src,w) pairs, broadcasts via shfl; gather loop unrolled x4 for MLP.
// ---------------------------------------------------------------------------
__global__ void lg_agg_kernel(const __hip_bfloat16* __restrict__ Xh,
                              const int2* __restrict__ csrw,
                              const int* __restrict__ off,
                              float* __restrict__ out, int n) {
    int node = (int)((blockIdx.x * (size_t)blockDim.x + threadIdx.x) >> 6);
    int lane = threadIdx.x & 63;
    if (node >= n) return;
    int beg = off[node], end = off[node + 1];
    float accx = 0.0f, accy = 0.0f;
    for (int base = beg; base < end; base += 64) {
        int cnt = min(end - base, 64);
        int2 my = make_int2(0, 0);
        if (lane < cnt) my = csrw[base + lane];
        int j = 0;
        for (; j + 3 < cnt; j += 4) {
            int   s0 = __shfl(my.x, j + 0), s1 = __shfl(my.x, j + 1);
            int   s2 = __shfl(my.x, j + 2), s3 = __shfl(my.x, j + 3);
            float w0 = __int_as_float(__shfl(my.y, j + 0));
            float w1 = __int_as_float(__shfl(my.y, j + 1));
            float w2 = __int_as_float(__shfl(my.y, j + 2));
            float w3 = __int_as_float(__shfl(my.y, j + 3));
            __hip_bfloat162 h0 = ((const __hip_bfloat162*)(Xh + (size_t)s0 * D))[lane];
            __hip_bfloat162 h1 = ((const __hip_bfloat162*)(Xh + (size_t)s1 * D))[lane];
            __hip_bfloat162 h2 = ((const __hip_bfloat162*)(Xh + (size_t)s2 * D))[lane];
            __hip_bfloat162 h3 = ((const __hip_bfloat162*)(Xh + (size_t)s3 * D))[lane];
            accx = fmaf(w0, __bfloat162float(h0.x), accx);
            accy = fmaf(w0, __bfloat162float(h0.y), accy);
            accx = fmaf(w1, __bfloat162float(h1.x), accx);
            accy = fmaf(w1, __bfloat162float(h1.y), accy);
            accx = fmaf(w2, __bfloat162float(h2.x), accx);
            accy = fmaf(w2, __bfloat162float(h2.y), accy);
            accx = fmaf(w3, __bfloat162float(h3.x), accx);
            accy = fmaf(w3, __bfloat162float(h3.y), accy);
        }
        for (; j < cnt; ++j) {
            int   s0 = __shfl(my.x, j);
            float w0 = __int_as_float(__shfl(my.y, j));
            __hip_bfloat162 h0 = ((const __hip_bfloat162*)(Xh + (size_t)s0 * D))[lane];
            accx = fmaf(w0, __bfloat162float(h0.x), accx);
            accy = fmaf(w0, __bfloat162float(h0.y), accy);
        }
    }
    float invd = 1.0f / fmaxf((float)(end - beg), 1.0f);
    ((float2*)(out + (size_t)node * D))[lane] = make_float2(accx * invd, accy * invd);
}

// f32-gather variant (used when ws too small for the bf16 X copy)
__global__ void lg_agg_f32_kernel(const float* __restrict__ X,
                                  const int2* __restrict__ csrw,
                                  const int* __restrict__ off,
                                  float* __restrict__ out, int n) {
    int node = (int)((blockIdx.x * (size_t)blockDim.x + threadIdx.x) >> 6);
    int lane = threadIdx.x & 63;
    if (node >= n) return;
    int beg = off[node], end = off[node + 1];
    float accx = 0.0f, accy = 0.0f;
    for (int base = beg; base < end; base += 64) {
        int cnt = min(end - base, 64);
        int2 my = make_int2(0, 0);
        if (lane < cnt) my = csrw[base + lane];
        for (int j = 0; j < cnt; ++j) {
            int   s0 = __shfl(my.x, j);
            float w0 = __int_as_float(__shfl(my.y, j));
            float2 x = ((const float2*)(X + (size_t)s0 * D))[lane];
            accx = fmaf(w0, x.x, accx);
            accy = fmaf(w0, x.y, accy);
        }
    }
    float invd = 1.0f / fmaxf((float)(end - beg), 1.0f);
    ((float2*)(out + (size_t)node * D))[lane] = make_float2(accx * invd, accy * invd);
}

// ---------------------------------------------------------------------------
// Minimal-workspace fallback: float-atomic scatter
// ---------------------------------------------------------------------------
__global__ void lg_scatter_kernel(const float* __restrict__ X,
                                  const float4* __restrict__ coeff,
                                  const int* __restrict__ src, const int* __restrict__ dst,
                                  float* __restrict__ out, int E) {
    int e = (int)((blockIdx.x * (size_t)blockDim.x + threadIdx.x) >> 6);
    int lane = threadIdx.x & 63;
    if (e >= E) return;
    int s = src[e], d = dst[e];
    float4 cs = coeff[s], cd = coeff[d];
    float se = cs.x * cd.x + cs.y * cd.y + cs.z * cd.z;
    float2 x = ((const float2*)(X + (size_t)s * D))[lane];
    atomicAdd(&out[(size_t)d * D + lane * 2 + 0], se * x.x);
    atomicAdd(&out[(size_t)d * D + lane * 2 + 1], se * x.y);
}

__global__ void lg_scale_kernel(float* __restrict__ out, const int* __restrict__ deg, int n) {
    int node = (int)((blockIdx.x * (size_t)blockDim.x + threadIdx.x) >> 6);
    int lane = threadIdx.x & 63;
    if (node >= n) return;
    float invd = 1.0f / fmaxf((float)deg[node], 1.0f);
    float2* p = (float2*)(out + (size_t)node * D);
    float2 v = p[lane];
    p[lane] = make_float2(v.x * invd, v.y * invd);
}

extern "C" void kernel_launch(void* const* d_in, const int* in_sizes, int n_in,
                              void* d_out, int out_size, void* d_ws, size_t ws_size,
                              hipStream_t stream) {
    const float* X   = (const float*)d_in[0];
    const int*   src = (const int*)d_in[1];
    const int*   dst = (const int*)d_in[2];
    const float* W   = (const float*)d_in[3];
    const float* b   = (const float*)d_in[4];
    float* out = (float*)d_out;
    int n = in_sizes[0] / D;
    int E = in_sizes[1];

    char* ws = (char*)d_ws;
    size_t p = 0;
    auto alloc = [&](size_t bytes) -> void* {
        void* r = ws + p;
        p = (p + bytes + 255) & ~(size_t)255;
        return r;
    };
    float4* coeff = (float4*)alloc((size_t)n * sizeof(float4));
    int*    deg   = (int*)alloc((size_t)n * sizeof(int));
    int*    cnt   = (int*)alloc((size_t)n * sizeof(int));
    int*    off   = (int*)alloc((size_t)(n + 1) * sizeof(int));
    size_t p_csr = p;
    int2*   csrw  = (int2*)alloc((size_t)E * sizeof(int2));
    size_t p_mid = p;                               // CSR path, f32 gathers
    __hip_bfloat16* Xh = (__hip_bfloat16*)alloc((size_t)n * D * sizeof(__hip_bfloat16));
    size_t p_full = p;                              // CSR path + bf16 X copy

    int node_blocks = (n + 3) / 4;      // 4 waves (nodes) per 256-thread block
    int edge_blocks = (E + 255) / 256;

    if (p_full <= ws_size || p_mid <= ws_size) {
        bool use_bf16 = (p_full <= ws_size);
        hipMemsetAsync(deg, 0, (size_t)n * sizeof(int), stream);
        hipMemsetAsync(cnt, 0, (size_t)n * sizeof(int), stream);
        lg_coeff_kernel<<<node_blocks, 256, 0, stream>>>(X, W, b, coeff,
                                                         use_bf16 ? Xh : nullptr, n);
        lg_deg_kernel<<<edge_blocks, 256, 0, stream>>>(dst, deg, E);
        lg_scan_kernel<<<1, 1024, 0, stream>>>(deg, off, n);
        lg_fill_kernel<<<edge_blocks, 256, 0, stream>>>(src, dst, coeff, off, cnt, csrw, E);
        if (use_bf16)
            lg_agg_kernel<<<node_blocks, 256, 0, stream>>>(Xh, csrw, off, out, n);
        else
            lg_agg_f32_kernel<<<node_blocks, 256, 0, stream>>>(X, csrw, off, out, n);
    } else {
        // minimal-workspace fallback (~1 MB): coeff + deg
        (void)p_csr;
        hipMemsetAsync(deg, 0, (size_t)n * sizeof(int), stream);
        hipMemsetAsync(out, 0, (size_t)n * D * sizeof(float), stream);
        lg_coeff_kernel<<<node_blocks, 256, 0, stream>>>(X, W, b, coeff, nullptr, n);
        lg_deg_kernel<<<edge_blocks, 256, 0, stream>>>(dst, deg, E);
        lg_scatter_kernel<<<(E + 3) / 4, 256, 0, stream>>>(X, coeff, src, dst, out, E);
        lg_scale_kernel<<<node_blocks, 256, 0, stream>>>(out, deg, n);
    }
}

// Round 3
// 139.200 us; speedup vs baseline: 1.9621x; 1.5189x over previous
//
#include <hip/hip_runtime.h>
#include <hip/hip_bf16.h>

#define D 128            // EMBED_DIM
#define G 3              // NUM_GROUPS

// ---------------------------------------------------------------------------
// Kernel 1: per-node linear(128->3) + softmax -> coeff[n] (float4, w=0)
// Also emits a bf16 copy of X for the gather phase (halves gather traffic).
// one wave (64 lanes) per node; each lane owns 2 feature dims (float2)
// ---------------------------------------------------------------------------
__global__ void lg_coeff_kernel(const float* __restrict__ X,
                                const float* __restrict__ W,
                                const float* __restrict__ b,
                                float4* __restrict__ coeff,
                                __hip_bfloat16* __restrict__ Xh,   // may be null
                                int n) {
    int node = (int)((blockIdx.x * (size_t)blockDim.x + threadIdx.x) >> 6);
    int lane = threadIdx.x & 63;
    if (node >= n) return;
    float2 x = ((const float2*)(X + (size_t)node * D))[lane];
    if (Xh) {
        __hip_bfloat162 h;
        h.x = __float2bfloat16(x.x);
        h.y = __float2bfloat16(x.y);
        ((__hip_bfloat162*)(Xh + (size_t)node * D))[lane] = h;
    }
    int d0 = lane * 2;
    float s0 = x.x * W[d0 * G + 0] + x.y * W[(d0 + 1) * G + 0];
    float s1 = x.x * W[d0 * G + 1] + x.y * W[(d0 + 1) * G + 1];
    float s2 = x.x * W[d0 * G + 2] + x.y * W[(d0 + 1) * G + 2];
    #pragma unroll
    for (int off = 32; off; off >>= 1) {
        s0 += __shfl_xor(s0, off);
        s1 += __shfl_xor(s1, off);
        s2 += __shfl_xor(s2, off);
    }
    s0 += b[0]; s1 += b[1]; s2 += b[2];     // T = 1.0
    float m = fmaxf(s0, fmaxf(s1, s2));
    float e0 = __expf(s0 - m), e1 = __expf(s1 - m), e2 = __expf(s2 - m);
    float inv = 1.0f / (e0 + e1 + e2);
    if (lane == 0) coeff[node] = make_float4(e0 * inv, e1 * inv, e2 * inv, 0.0f);
}

// ---------------------------------------------------------------------------
// Kernel 2: degree histogram (int atomics)
// ---------------------------------------------------------------------------
__global__ void lg_deg_kernel(const int* __restrict__ dst, int* __restrict__ deg, int E) {
    int e = (int)(blockIdx.x * (size_t)blockDim.x + threadIdx.x);
    if (e < E) atomicAdd(&deg[dst[e]], 1);
}

// ---------------------------------------------------------------------------
// Kernel 3a: block-level exclusive scan (coalesced). 256 elems per block via
// LDS Hillis-Steele; emits per-block totals. off[n]=E written directly.
// ---------------------------------------------------------------------------
__global__ void lg_scan_a_kernel(const int* __restrict__ deg, int* __restrict__ off,
                                 int* __restrict__ bsum, int n, int E) {
    __shared__ int lds[256];
    int tid = threadIdx.x;
    int t = blockIdx.x * 256 + tid;
    int v = (t < n) ? deg[t] : 0;
    lds[tid] = v;
    __syncthreads();
    #pragma unroll
    for (int d = 1; d < 256; d <<= 1) {
        int y = (tid >= d) ? lds[tid - d] : 0;
        __syncthreads();
        lds[tid] += y;
        __syncthreads();
    }
    if (t < n) off[t] = lds[tid] - v;            // exclusive within block
    if (tid == 255) bsum[blockIdx.x] = lds[255]; // block total
    if (t == 0) off[n] = E;                      // grand total known a priori
}

// ---------------------------------------------------------------------------
// Kernel 3b: add prefix of block sums. Each block reduces bsum[0..b) (tiny,
// L2-hot) with wave shuffles and adds it to its 256 off entries.
// ---------------------------------------------------------------------------
__global__ void lg_scan_b_kernel(int* __restrict__ off, const int* __restrict__ bsum,
                                 int n) {
    int b = blockIdx.x;
    int tid = threadIdx.x;
    int s = 0;
    for (int i = tid; i < b; i += 256) s += bsum[i];
    #pragma unroll
    for (int o = 32; o; o >>= 1) s += __shfl_xor(s, o);
    __shared__ int ws[4];
    if ((tid & 63) == 0) ws[tid >> 6] = s;
    __syncthreads();
    int S = ws[0] + ws[1] + ws[2] + ws[3];
    int t = b * 256 + tid;
    if (t < n) off[t] += S;
}

// ---------------------------------------------------------------------------
// Kernel 4: counting-sort edges by dst into CSR, with per-edge scalar weight
// w_e = dot3(coeff[dst], coeff[src]) baked in. Payload int2 = (src, w-bits).
// ---------------------------------------------------------------------------
__global__ void lg_fill_kernel(const int* __restrict__ src, const int* __restrict__ dst,
                               const float4* __restrict__ coeff,
                               const int* __restrict__ off, int* __restrict__ cnt,
                               int2* __restrict__ csrw, int E) {
    int e = (int)(blockIdx.x * (size_t)blockDim.x + threadIdx.x);
    if (e >= E) return;
    int s = src[e], d = dst[e];
    float4 cs = coeff[s], cd = coeff[d];
    float w = cs.x * cd.x + cs.y * cd.y + cs.z * cd.z;
    int pos = off[d] + atomicAdd(&cnt[d], 1);
    csrw[pos] = make_int2(s, __float_as_int(w));
}

// ---------------------------------------------------------------------------
// Kernel 5: per-node aggregation, bf16 gathers.
// One wave per dst node; lanes own 2 dims. Wave coalesce-loads up to 64
// (src,w) pairs, broadcasts via shfl; gather loop unrolled x4 for MLP.
// ---------------------------------------------------------------------------
__global__ void lg_agg_kernel(const __hip_bfloat16* __restrict__ Xh,
                              const int2* __restrict__ csrw,
                              const int* __restrict__ off,
                              float* __restrict__ out, int n) {
    int node = (int)((blockIdx.x * (size_t)blockDim.x + threadIdx.x) >> 6);
    int lane = threadIdx.x & 63;
    if (node >= n) return;
    int beg = off[node], end = off[node + 1];
    float accx = 0.0f, accy = 0.0f;
    for (int base = beg; base < end; base += 64) {
        int cnt = min(end - base, 64);
        int2 my = make_int2(0, 0);
        if (lane < cnt) my = csrw[base + lane];
        int j = 0;
        for (; j + 3 < cnt; j += 4) {
            int   s0 = __shfl(my.x, j + 0), s1 = __shfl(my.x, j + 1);
            int   s2 = __shfl(my.x, j + 2), s3 = __shfl(my.x, j + 3);
            float w0 = __int_as_float(__shfl(my.y, j + 0));
            float w1 = __int_as_float(__shfl(my.y, j + 1));
            float w2 = __int_as_float(__shfl(my.y, j + 2));
            float w3 = __int_as_float(__shfl(my.y, j + 3));
            __hip_bfloat162 h0 = ((const __hip_bfloat162*)(Xh + (size_t)s0 * D))[lane];
            __hip_bfloat162 h1 = ((const __hip_bfloat162*)(Xh + (size_t)s1 * D))[lane];
            __hip_bfloat162 h2 = ((const __hip_bfloat162*)(Xh + (size_t)s2 * D))[lane];
            __hip_bfloat162 h3 = ((const __hip_bfloat162*)(Xh + (size_t)s3 * D))[lane];
            accx = fmaf(w0, __bfloat162float(h0.x), accx);
            accy = fmaf(w0, __bfloat162float(h0.y), accy);
            accx = fmaf(w1, __bfloat162float(h1.x), accx);
            accy = fmaf(w1, __bfloat162float(h1.y), accy);
            accx = fmaf(w2, __bfloat162float(h2.x), accx);
            accy = fmaf(w2, __bfloat162float(h2.y), accy);
            accx = fmaf(w3, __bfloat162float(h3.x), accx);
            accy = fmaf(w3, __bfloat162float(h3.y), accy);
        }
        for (; j < cnt; ++j) {
            int   s0 = __shfl(my.x, j);
            float w0 = __int_as_float(__shfl(my.y, j));
            __hip_bfloat162 h0 = ((const __hip_bfloat162*)(Xh + (size_t)s0 * D))[lane];
            accx = fmaf(w0, __bfloat162float(h0.x), accx);
            accy = fmaf(w0, __bfloat162float(h0.y), accy);
        }
    }
    float invd = 1.0f / fmaxf((float)(end - beg), 1.0f);
    ((float2*)(out + (size_t)node * D))[lane] = make_float2(accx * invd, accy * invd);
}

// f32-gather variant (used when ws too small for the bf16 X copy)
__global__ void lg_agg_f32_kernel(const float* __restrict__ X,
                                  const int2* __restrict__ csrw,
                                  const int* __restrict__ off,
                                  float* __restrict__ out, int n) {
    int node = (int)((blockIdx.x * (size_t)blockDim.x + threadIdx.x) >> 6);
    int lane = threadIdx.x & 63;
    if (node >= n) return;
    int beg = off[node], end = off[node + 1];
    float accx = 0.0f, accy = 0.0f;
    for (int base = beg; base < end; base += 64) {
        int cnt = min(end - base, 64);
        int2 my = make_int2(0, 0);
        if (lane < cnt) my = csrw[base + lane];
        for (int j = 0; j < cnt; ++j) {
            int   s0 = __shfl(my.x, j);
            float w0 = __int_as_float(__shfl(my.y, j));
            float2 x = ((const float2*)(X + (size_t)s0 * D))[lane];
            accx = fmaf(w0, x.x, accx);
            accy = fmaf(w0, x.y, accy);
        }
    }
    float invd = 1.0f / fmaxf((float)(end - beg), 1.0f);
    ((float2*)(out + (size_t)node * D))[lane] = make_float2(accx * invd, accy * invd);
}

// ---------------------------------------------------------------------------
// Minimal-workspace fallback: float-atomic scatter
// ---------------------------------------------------------------------------
__global__ void lg_scatter_kernel(const float* __restrict__ X,
                                  const float4* __restrict__ coeff,
                                  const int* __restrict__ src, const int* __restrict__ dst,
                                  float* __restrict__ out, int E) {
    int e = (int)((blockIdx.x * (size_t)blockDim.x + threadIdx.x) >> 6);
    int lane = threadIdx.x & 63;
    if (e >= E) return;
    int s = src[e], d = dst[e];
    float4 cs = coeff[s], cd = coeff[d];
    float se = cs.x * cd.x + cs.y * cd.y + cs.z * cd.z;
    float2 x = ((const float2*)(X + (size_t)s * D))[lane];
    atomicAdd(&out[(size_t)d * D + lane * 2 + 0], se * x.x);
    atomicAdd(&out[(size_t)d * D + lane * 2 + 1], se * x.y);
}

__global__ void lg_scale_kernel(float* __restrict__ out, const int* __restrict__ deg, int n) {
    int node = (int)((blockIdx.x * (size_t)blockDim.x + threadIdx.x) >> 6);
    int lane = threadIdx.x & 63;
    if (node >= n) return;
    float invd = 1.0f / fmaxf((float)deg[node], 1.0f);
    float2* p = (float2*)(out + (size_t)node * D);
    float2 v = p[lane];
    p[lane] = make_float2(v.x * invd, v.y * invd);
}

extern "C" void kernel_launch(void* const* d_in, const int* in_sizes, int n_in,
                              void* d_out, int out_size, void* d_ws, size_t ws_size,
                              hipStream_t stream) {
    const float* X   = (const float*)d_in[0];
    const int*   src = (const int*)d_in[1];
    const int*   dst = (const int*)d_in[2];
    const float* W   = (const float*)d_in[3];
    const float* b   = (const float*)d_in[4];
    float* out = (float*)d_out;
    int n = in_sizes[0] / D;
    int E = in_sizes[1];

    int nb = (n + 255) / 256;           // scan blocks

    char* ws = (char*)d_ws;
    size_t p = 0;
    auto alloc = [&](size_t bytes) -> void* {
        void* r = ws + p;
        p = (p + bytes + 255) & ~(size_t)255;
        return r;
    };
    float4* coeff = (float4*)alloc((size_t)n * sizeof(float4));
    int*    deg   = (int*)alloc((size_t)n * sizeof(int));
    int*    cnt   = (int*)alloc((size_t)n * sizeof(int));
    int*    off   = (int*)alloc((size_t)(n + 1) * sizeof(int));
    int*    bsum  = (int*)alloc((size_t)nb * sizeof(int));
    int2*   csrw  = (int2*)alloc((size_t)E * sizeof(int2));
    size_t p_mid = p;                               // CSR path, f32 gathers
    __hip_bfloat16* Xh = (__hip_bfloat16*)alloc((size_t)n * D * sizeof(__hip_bfloat16));
    size_t p_full = p;                              // CSR path + bf16 X copy

    int node_blocks = (n + 3) / 4;      // 4 waves (nodes) per 256-thread block
    int edge_blocks = (E + 255) / 256;

    if (p_full <= ws_size || p_mid <= ws_size) {
        bool use_bf16 = (p_full <= ws_size);
        // deg and cnt are adjacent in ws: one memset covers both
        hipMemsetAsync(deg, 0, (size_t)((char*)cnt - (char*)deg) + (size_t)n * sizeof(int), stream);
        lg_coeff_kernel<<<node_blocks, 256, 0, stream>>>(X, W, b, coeff,
                                                         use_bf16 ? Xh : nullptr, n);
        lg_deg_kernel<<<edge_blocks, 256, 0, stream>>>(dst, deg, E);
        lg_scan_a_kernel<<<nb, 256, 0, stream>>>(deg, off, bsum, n, E);
        lg_scan_b_kernel<<<nb, 256, 0, stream>>>(off, bsum, n);
        lg_fill_kernel<<<edge_blocks, 256, 0, stream>>>(src, dst, coeff, off, cnt, csrw, E);
        if (use_bf16)
            lg_agg_kernel<<<node_blocks, 256, 0, stream>>>(Xh, csrw, off, out, n);
        else
            lg_agg_f32_kernel<<<node_blocks, 256, 0, stream>>>(X, csrw, off, out, n);
    } else {
        // minimal-workspace fallback (~1 MB): coeff + deg
        hipMemsetAsync(deg, 0, (size_t)n * sizeof(int), stream);
        hipMemsetAsync(out, 0, (size_t)n * D * sizeof(float), stream);
        lg_coeff_kernel<<<node_blocks, 256, 0, stream>>>(X, W, b, coeff, nullptr, n);
        lg_deg_kernel<<<edge_blocks, 256, 0, stream>>>(dst, deg, E);
        lg_scatter_kernel<<<(E + 3) / 4, 256, 0, stream>>>(X, coeff, src, dst, out, E);
        lg_scale_kernel<<<node_blocks, 256, 0, stream>>>(out, deg, n);
    }
}

// Round 4
// 138.308 us; speedup vs baseline: 1.9747x; 1.0064x over previous
//
#include <hip/hip_runtime.h>
#include <hip/hip_bf16.h>

#define D 128            // EMBED_DIM
#define G 3              // NUM_GROUPS

// ---------------------------------------------------------------------------
// Kernel 1: per-node linear(128->3) + softmax -> coeff[n] (float4, w=0)
// Also emits a bf16 copy of X for the gather phase (halves gather traffic).
// one wave (64 lanes) per node; each lane owns 2 feature dims (float2)
// ---------------------------------------------------------------------------
__global__ void lg_coeff_kernel(const float* __restrict__ X,
                                const float* __restrict__ W,
                                const float* __restrict__ b,
                                float4* __restrict__ coeff,
                                __hip_bfloat16* __restrict__ Xh,   // may be null
                                int n) {
    int node = (int)((blockIdx.x * (size_t)blockDim.x + threadIdx.x) >> 6);
    int lane = threadIdx.x & 63;
    if (node >= n) return;
    float2 x = ((const float2*)(X + (size_t)node * D))[lane];
    if (Xh) {
        __hip_bfloat162 h;
        h.x = __float2bfloat16(x.x);
        h.y = __float2bfloat16(x.y);
        ((__hip_bfloat162*)(Xh + (size_t)node * D))[lane] = h;
    }
    int d0 = lane * 2;
    float s0 = x.x * W[d0 * G + 0] + x.y * W[(d0 + 1) * G + 0];
    float s1 = x.x * W[d0 * G + 1] + x.y * W[(d0 + 1) * G + 1];
    float s2 = x.x * W[d0 * G + 2] + x.y * W[(d0 + 1) * G + 2];
    #pragma unroll
    for (int off = 32; off; off >>= 1) {
        s0 += __shfl_xor(s0, off);
        s1 += __shfl_xor(s1, off);
        s2 += __shfl_xor(s2, off);
    }
    s0 += b[0]; s1 += b[1]; s2 += b[2];     // T = 1.0
    float m = fmaxf(s0, fmaxf(s1, s2));
    float e0 = __expf(s0 - m), e1 = __expf(s1 - m), e2 = __expf(s2 - m);
    float inv = 1.0f / (e0 + e1 + e2);
    if (lane == 0) coeff[node] = make_float4(e0 * inv, e1 * inv, e2 * inv, 0.0f);
}

// ---------------------------------------------------------------------------
// Kernel 2: degree histogram (int atomics)
// ---------------------------------------------------------------------------
__global__ void lg_deg_kernel(const int* __restrict__ dst, int* __restrict__ deg, int E) {
    int e = (int)(blockIdx.x * (size_t)blockDim.x + threadIdx.x);
    if (e < E) atomicAdd(&deg[dst[e]], 1);
}

// ---------------------------------------------------------------------------
// Kernel 3a: block-level exclusive scan (coalesced). 256 elems per block via
// LDS Hillis-Steele; emits per-block totals. off[n]=E written directly.
// ---------------------------------------------------------------------------
__global__ void lg_scan_a_kernel(const int* __restrict__ deg, int* __restrict__ off,
                                 int* __restrict__ bsum, int n, int E) {
    __shared__ int lds[256];
    int tid = threadIdx.x;
    int t = blockIdx.x * 256 + tid;
    int v = (t < n) ? deg[t] : 0;
    lds[tid] = v;
    __syncthreads();
    #pragma unroll
    for (int d = 1; d < 256; d <<= 1) {
        int y = (tid >= d) ? lds[tid - d] : 0;
        __syncthreads();
        lds[tid] += y;
        __syncthreads();
    }
    if (t < n) off[t] = lds[tid] - v;            // exclusive within block
    if (tid == 255) bsum[blockIdx.x] = lds[255]; // block total
    if (t == 0) off[n] = E;                      // grand total known a priori
}

// ---------------------------------------------------------------------------
// Kernel 3b: add prefix of block sums.
// ---------------------------------------------------------------------------
__global__ void lg_scan_b_kernel(int* __restrict__ off, const int* __restrict__ bsum,
                                 int n) {
    int b = blockIdx.x;
    int tid = threadIdx.x;
    int s = 0;
    for (int i = tid; i < b; i += 256) s += bsum[i];
    #pragma unroll
    for (int o = 32; o; o >>= 1) s += __shfl_xor(s, o);
    __shared__ int ws[4];
    if ((tid & 63) == 0) ws[tid >> 6] = s;
    __syncthreads();
    int S = ws[0] + ws[1] + ws[2] + ws[3];
    int t = b * 256 + tid;
    if (t < n) off[t] += S;
}

// ---------------------------------------------------------------------------
// Kernel 4: counting-sort edges by dst into CSR with PACKED 4-byte records:
//   rec = src (low 16) | bf16(w) bits (high 16),  w = dot3(coeff_d, coeff_s)
// Requires n <= 65536. 4B records halve the scattered-write line footprint.
// ---------------------------------------------------------------------------
__global__ void lg_fill_packed_kernel(const int* __restrict__ src, const int* __restrict__ dst,
                                      const float4* __restrict__ coeff,
                                      const int* __restrict__ off, int* __restrict__ cnt,
                                      unsigned int* __restrict__ csr, int E) {
    int e = (int)(blockIdx.x * (size_t)blockDim.x + threadIdx.x);
    if (e >= E) return;
    int s = src[e], d = dst[e];
    float4 cs = coeff[s], cd = coeff[d];
    float w = cs.x * cd.x + cs.y * cd.y + cs.z * cd.z;
    // round-to-nearest-even bf16
    unsigned int wb = __float_as_uint(w);
    wb += 0x7FFFu + ((wb >> 16) & 1u);
    int pos = off[d] + atomicAdd(&cnt[d], 1);
    csr[pos] = ((unsigned int)s & 0xFFFFu) | (wb & 0xFFFF0000u);
}

// ---------------------------------------------------------------------------
// Kernel 5: per-node aggregation, bf16 gathers, packed records.
// One wave per dst node; lanes own 2 dims. Wave coalesce-loads up to 64
// records, broadcasts via shfl; gather loop unrolled x4 for MLP.
// w decode is free: bf16 bits are the top 16 of the f32 pattern.
// ---------------------------------------------------------------------------
__global__ void lg_agg_kernel(const __hip_bfloat16* __restrict__ Xh,
                              const unsigned int* __restrict__ csr,
                              const int* __restrict__ off,
                              float* __restrict__ out, int n) {
    int node = (int)((blockIdx.x * (size_t)blockDim.x + threadIdx.x) >> 6);
    int lane = threadIdx.x & 63;
    if (node >= n) return;
    int beg = off[node], end = off[node + 1];
    float accx = 0.0f, accy = 0.0f;
    for (int base = beg; base < end; base += 64) {
        int cnt = min(end - base, 64);
        unsigned int my = 0;
        if (lane < cnt) my = csr[base + lane];
        int j = 0;
        for (; j + 3 < cnt; j += 4) {
            unsigned int r0 = __shfl(my, j + 0), r1 = __shfl(my, j + 1);
            unsigned int r2 = __shfl(my, j + 2), r3 = __shfl(my, j + 3);
            int s0 = (int)(r0 & 0xFFFFu), s1 = (int)(r1 & 0xFFFFu);
            int s2 = (int)(r2 & 0xFFFFu), s3 = (int)(r3 & 0xFFFFu);
            float w0 = __uint_as_float(r0 & 0xFFFF0000u);
            float w1 = __uint_as_float(r1 & 0xFFFF0000u);
            float w2 = __uint_as_float(r2 & 0xFFFF0000u);
            float w3 = __uint_as_float(r3 & 0xFFFF0000u);
            __hip_bfloat162 h0 = ((const __hip_bfloat162*)(Xh + (size_t)s0 * D))[lane];
            __hip_bfloat162 h1 = ((const __hip_bfloat162*)(Xh + (size_t)s1 * D))[lane];
            __hip_bfloat162 h2 = ((const __hip_bfloat162*)(Xh + (size_t)s2 * D))[lane];
            __hip_bfloat162 h3 = ((const __hip_bfloat162*)(Xh + (size_t)s3 * D))[lane];
            accx = fmaf(w0, __bfloat162float(h0.x), accx);
            accy = fmaf(w0, __bfloat162float(h0.y), accy);
            accx = fmaf(w1, __bfloat162float(h1.x), accx);
            accy = fmaf(w1, __bfloat162float(h1.y), accy);
            accx = fmaf(w2, __bfloat162float(h2.x), accx);
            accy = fmaf(w2, __bfloat162float(h2.y), accy);
            accx = fmaf(w3, __bfloat162float(h3.x), accx);
            accy = fmaf(w3, __bfloat162float(h3.y), accy);
        }
        for (; j < cnt; ++j) {
            unsigned int r0 = __shfl(my, j);
            int s0 = (int)(r0 & 0xFFFFu);
            float w0 = __uint_as_float(r0 & 0xFFFF0000u);
            __hip_bfloat162 h0 = ((const __hip_bfloat162*)(Xh + (size_t)s0 * D))[lane];
            accx = fmaf(w0, __bfloat162float(h0.x), accx);
            accy = fmaf(w0, __bfloat162float(h0.y), accy);
        }
    }
    float invd = 1.0f / fmaxf((float)(end - beg), 1.0f);
    ((float2*)(out + (size_t)node * D))[lane] = make_float2(accx * invd, accy * invd);
}

// f32-gather variant (used when ws too small for the bf16 X copy)
__global__ void lg_agg_f32_kernel(const float* __restrict__ X,
                                  const unsigned int* __restrict__ csr,
                                  const int* __restrict__ off,
                                  float* __restrict__ out, int n) {
    int node = (int)((blockIdx.x * (size_t)blockDim.x + threadIdx.x) >> 6);
    int lane = threadIdx.x & 63;
    if (node >= n) return;
    int beg = off[node], end = off[node + 1];
    float accx = 0.0f, accy = 0.0f;
    for (int base = beg; base < end; base += 64) {
        int cnt = min(end - base, 64);
        unsigned int my = 0;
        if (lane < cnt) my = csr[base + lane];
        for (int j = 0; j < cnt; ++j) {
            unsigned int r0 = __shfl(my, j);
            int s0 = (int)(r0 & 0xFFFFu);
            float w0 = __uint_as_float(r0 & 0xFFFF0000u);
            float2 x = ((const float2*)(X + (size_t)s0 * D))[lane];
            accx = fmaf(w0, x.x, accx);
            accy = fmaf(w0, x.y, accy);
        }
    }
    float invd = 1.0f / fmaxf((float)(end - beg), 1.0f);
    ((float2*)(out + (size_t)node * D))[lane] = make_float2(accx * invd, accy * invd);
}

// ---------------------------------------------------------------------------
// Minimal-workspace / large-n fallback: float-atomic scatter
// ---------------------------------------------------------------------------
__global__ void lg_scatter_kernel(const float* __restrict__ X,
                                  const float4* __restrict__ coeff,
                                  const int* __restrict__ src, const int* __restrict__ dst,
                                  float* __restrict__ out, int E) {
    int e = (int)((blockIdx.x * (size_t)blockDim.x + threadIdx.x) >> 6);
    int lane = threadIdx.x & 63;
    if (e >= E) return;
    int s = src[e], d = dst[e];
    float4 cs = coeff[s], cd = coeff[d];
    float se = cs.x * cd.x + cs.y * cd.y + cs.z * cd.z;
    float2 x = ((const float2*)(X + (size_t)s * D))[lane];
    atomicAdd(&out[(size_t)d * D + lane * 2 + 0], se * x.x);
    atomicAdd(&out[(size_t)d * D + lane * 2 + 1], se * x.y);
}

__global__ void lg_scale_kernel(float* __restrict__ out, const int* __restrict__ deg, int n) {
    int node = (int)((blockIdx.x * (size_t)blockDim.x + threadIdx.x) >> 6);
    int lane = threadIdx.x & 63;
    if (node >= n) return;
    float invd = 1.0f / fmaxf((float)deg[node], 1.0f);
    float2* p = (float2*)(out + (size_t)node * D);
    float2 v = p[lane];
    p[lane] = make_float2(v.x * invd, v.y * invd);
}

extern "C" void kernel_launch(void* const* d_in, const int* in_sizes, int n_in,
                              void* d_out, int out_size, void* d_ws, size_t ws_size,
                              hipStream_t stream) {
    const float* X   = (const float*)d_in[0];
    const int*   src = (const int*)d_in[1];
    const int*   dst = (const int*)d_in[2];
    const float* W   = (const float*)d_in[3];
    const float* b   = (const float*)d_in[4];
    float* out = (float*)d_out;
    int n = in_sizes[0] / D;
    int E = in_sizes[1];

    int nb = (n + 255) / 256;           // scan blocks

    char* ws = (char*)d_ws;
    size_t p = 0;
    auto alloc = [&](size_t bytes) -> void* {
        void* r = ws + p;
        p = (p + bytes + 255) & ~(size_t)255;
        return r;
    };
    float4* coeff = (float4*)alloc((size_t)n * sizeof(float4));
    int*    deg   = (int*)alloc((size_t)n * sizeof(int));
    int*    cnt   = (int*)alloc((size_t)n * sizeof(int));
    int*    off   = (int*)alloc((size_t)(n + 1) * sizeof(int));
    int*    bsum  = (int*)alloc((size_t)nb * sizeof(int));
    unsigned int* csr = (unsigned int*)alloc((size_t)E * sizeof(unsigned int));
    size_t p_mid = p;                               // CSR path, f32 gathers
    __hip_bfloat16* Xh = (__hip_bfloat16*)alloc((size_t)n * D * sizeof(__hip_bfloat16));
    size_t p_full = p;                              // CSR path + bf16 X copy

    int node_blocks = (n + 3) / 4;      // 4 waves (nodes) per 256-thread block
    int edge_blocks = (E + 255) / 256;

    bool packed_ok = (n <= 65536);
    if (packed_ok && (p_full <= ws_size || p_mid <= ws_size)) {
        bool use_bf16 = (p_full <= ws_size);
        // deg and cnt are adjacent in ws: one memset covers both
        hipMemsetAsync(deg, 0, (size_t)((char*)cnt - (char*)deg) + (size_t)n * sizeof(int), stream);
        lg_coeff_kernel<<<node_blocks, 256, 0, stream>>>(X, W, b, coeff,
                                                         use_bf16 ? Xh : nullptr, n);
        lg_deg_kernel<<<edge_blocks, 256, 0, stream>>>(dst, deg, E);
        lg_scan_a_kernel<<<nb, 256, 0, stream>>>(deg, off, bsum, n, E);
        lg_scan_b_kernel<<<nb, 256, 0, stream>>>(off, bsum, n);
        lg_fill_packed_kernel<<<edge_blocks, 256, 0, stream>>>(src, dst, coeff, off, cnt, csr, E);
        if (use_bf16)
            lg_agg_kernel<<<node_blocks, 256, 0, stream>>>(Xh, csr, off, out, n);
        else
            lg_agg_f32_kernel<<<node_blocks, 256, 0, stream>>>(X, csr, off, out, n);
    } else {
        // fallback (~1 MB): coeff + deg; atomic scatter
        hipMemsetAsync(deg, 0, (size_t)n * sizeof(int), stream);
        hipMemsetAsync(out, 0, (size_t)n * D * sizeof(float), stream);
        lg_coeff_kernel<<<node_blocks, 256, 0, stream>>>(X, W, b, coeff, nullptr, n);
        lg_deg_kernel<<<edge_blocks, 256, 0, stream>>>(dst, deg, E);
        lg_scatter_kernel<<<(E + 3) / 4, 256, 0, stream>>>(X, coeff, src, dst, out, E);
        lg_scale_kernel<<<node_blocks, 256, 0, stream>>>(out, deg, n);
    }
}